// Round 14
// baseline (584.355 us; speedup 1.0000x reference)
//
#include <hip/hip_runtime.h>
#include <hip/hip_bf16.h>
#include <stdint.h>

typedef __attribute__((ext_vector_type(8))) short bf16x8;
typedef __attribute__((ext_vector_type(4))) float f32x4;
typedef __attribute__((ext_vector_type(4))) unsigned short u16x4;
typedef __attribute__((ext_vector_type(8))) unsigned short u16x8;

#define DEV __device__ __forceinline__

DEV unsigned short f2bf(float f) {
  union { __hip_bfloat16 h; unsigned short u; } cv;
  cv.h = __float2bfloat16(f);
  return cv.u;
}

// global -> LDS direct load, 16B per lane. LDS dest is wave-uniform base;
// HW adds lane*16. Global src is per-lane.
DEV void gload_lds16(const void* g, void* l) {
  __builtin_amdgcn_global_load_lds(
      (__attribute__((address_space(1))) void*)(uintptr_t)g,
      (__attribute__((address_space(3))) void*)(uint32_t)(uintptr_t)l,
      16, 0, 0);
}

// ---------------------------------------------------------------- prep ----
__global__ __launch_bounds__(256) void k_convert(const float* __restrict__ in,
                                                 unsigned short* __restrict__ out,
                                                 int n8) {
  int i = blockIdx.x * 256 + threadIdx.x;
  if (i >= n8) return;
  const float4* p = (const float4*)in + (size_t)i * 2;
  float4 a = p[0], b = p[1];
  u16x8 o;
  o[0] = f2bf(a.x); o[1] = f2bf(a.y); o[2] = f2bf(a.z); o[3] = f2bf(a.w);
  o[4] = f2bf(b.x); o[5] = f2bf(b.y); o[6] = f2bf(b.z); o[7] = f2bf(b.w);
  *((u16x8*)out + (size_t)i) = o;
}

// in: [R][C] f32  ->  out: [C][R] bf16
__global__ __launch_bounds__(256) void k_transpose_bf16(const float* __restrict__ in,
                                                        unsigned short* __restrict__ out,
                                                        int R, int C) {
  __shared__ float tile[32][33];
  const int t = threadIdx.x;
  const int c0 = blockIdx.x * 32, r0 = blockIdx.y * 32;
  {
    int r = t >> 3, c4 = (t & 7) * 4;
    float4 v = *(const float4*)&in[(size_t)(r0 + r) * C + c0 + c4];
    tile[r][c4] = v.x; tile[r][c4 + 1] = v.y; tile[r][c4 + 2] = v.z; tile[r][c4 + 3] = v.w;
  }
  __syncthreads();
  int c = t >> 3, r4 = (t & 7) * 4;
  u16x4 o;
  o[0] = f2bf(tile[r4 + 0][c]); o[1] = f2bf(tile[r4 + 1][c]);
  o[2] = f2bf(tile[r4 + 2][c]); o[3] = f2bf(tile[r4 + 3][c]);
  *(u16x4*)&out[(size_t)(c0 + c) * R + r0 + r4] = o;
}

// -------------------------------------- 256x192 8-phase qkv GEMM (T4) ----
// (round-9 version — best measured of 7 schedule variants: 141.5us band)
__global__ __launch_bounds__(512, 2) void k_gemm_qkv(
    const unsigned short* __restrict__ A,
    const unsigned short* __restrict__ Bt,
    unsigned short* __restrict__ qb,
    unsigned short* __restrict__ kb,
    unsigned short* __restrict__ vt,
    const float* __restrict__ freqs) {
  constexpr int Kdim = 2048;
  __shared__ unsigned short As[2][16384];  // [buf][khalf*8192 + slot*8]
  __shared__ unsigned short Bs[2][12288];  // [buf][khalf*6144 + slot*8]
  const int t = threadIdx.x;
  const int lane = t & 63, wid = t >> 6;
  const int l15 = lane & 15, l4 = (lane >> 4) & 3;
  const int wm = wid >> 2, wn = wid & 3;
  const int bid = blockIdx.x;
  const int wg = (bid & 7) * 64 + (bid >> 3);
  const int by = wg & 15, bx = wg >> 4;  // by 0..15, bx 0..31
  const int m0 = by * 256, n0 = bx * 192;

  f32x4 acc[8][3];
#pragma unroll
  for (int i = 0; i < 8; i++)
#pragma unroll
    for (int j = 0; j < 3; j++) acc[i][j] = (f32x4)0.f;

  auto stageUA = [&](unsigned short* dstUnit, const unsigned short* src, int khalf) {
#pragma unroll
    for (int cb = 0; cb < 2; cb++) {
      int slotu = cb * 512 + wid * 64;
      int slot = slotu + lane;
      int row = slot >> 2, s = slot & 3;
      int c = s ^ ((row >> 1) & 3);
      gload_lds16(src + (size_t)row * Kdim + khalf * 32 + c * 8,
                  dstUnit + slotu * 8);
    }
  };
  auto stageUB = [&](unsigned short* dstUnit, const unsigned short* src, int khalf) {
    {
      int slotu = wid * 64;
      int slot = slotu + lane;
      int row = slot >> 2, s = slot & 3;
      int c = s ^ ((row >> 1) & 3);
      gload_lds16(src + (size_t)row * Kdim + khalf * 32 + c * 8,
                  dstUnit + slotu * 8);
    }
    {
      int slotu = 512 + (wid & 3) * 64;
      int slot = slotu + lane;
      int row = slot >> 2, s = slot & 3;
      int c = s ^ ((row >> 1) & 3);
      gload_lds16(src + (size_t)row * Kdim + khalf * 32 + c * 8,
                  dstUnit + slotu * 8);
    }
  };

  auto rdA2 = [&](int buf, int kk, int mh, bf16x8 (&f)[4]) {
    const unsigned short* base = &As[buf][kk * 8192];
#pragma unroll
    for (int mi = 0; mi < 4; mi++) {
      int row = wm * 128 + mh * 64 + mi * 16 + l15;
      int s = l4 ^ ((row >> 1) & 3);
      f[mi] = *(const bf16x8*)&base[row * 32 + s * 8];
    }
  };
  auto rdB2 = [&](int buf, int kk, bf16x8 (&f)[3]) {
    const unsigned short* base = &Bs[buf][kk * 6144];
#pragma unroll
    for (int ni = 0; ni < 3; ni++) {
      int row = wn * 48 + ni * 16 + l15;
      int s = l4 ^ ((row >> 1) & 3);
      f[ni] = *(const bf16x8*)&base[row * 32 + s * 8];
    }
  };
  auto mmaP = [&](bf16x8 (&a4)[4], bf16x8 (&b3)[3], int mib) {
    __builtin_amdgcn_s_setprio(1);
#pragma unroll
    for (int mi = 0; mi < 4; mi++)
#pragma unroll
      for (int ni = 0; ni < 3; ni++)
        acc[mib + mi][ni] = __builtin_amdgcn_mfma_f32_16x16x32_bf16(
            a4[mi], b3[ni], acc[mib + mi][ni], 0, 0, 0);
    __builtin_amdgcn_s_setprio(0);
  };

  const unsigned short* Abase = A + (size_t)m0 * Kdim;
  const unsigned short* Bbase = Bt + (size_t)n0 * Kdim;

  stageUA(&As[0][0], Abase, 0);
  stageUB(&Bs[0][0], Bbase, 0);
  stageUA(&As[0][8192], Abase, 1);
  stageUB(&Bs[0][6144], Bbase, 1);
  stageUA(&As[1][0], Abase + 64, 0);
  stageUB(&Bs[1][0], Bbase + 64, 0);
  asm volatile("s_waitcnt vmcnt(8)" ::: "memory");
  __builtin_amdgcn_s_barrier();

  bf16x8 a4[4], b3[3];
  for (int j = 0; j < 32; j++) {
    const int buf = j & 1;

    rdA2(buf, 0, 0, a4);
    rdB2(buf, 0, b3);
    if (j + 1 < 32) {
      stageUA(&As[buf ^ 1][8192], Abase + (j + 1) * 64, 1);
      stageUB(&Bs[buf ^ 1][6144], Bbase + (j + 1) * 64, 1);
    }
    __builtin_amdgcn_s_barrier();
    mmaP(a4, b3, 0);
    __builtin_amdgcn_s_barrier();

    rdA2(buf, 0, 1, a4);
    __builtin_amdgcn_s_barrier();
    mmaP(a4, b3, 4);
    if (j < 31) asm volatile("s_waitcnt vmcnt(8) lgkmcnt(0)" ::: "memory");
    else        asm volatile("s_waitcnt vmcnt(0) lgkmcnt(0)" ::: "memory");
    __builtin_amdgcn_s_barrier();

    rdA2(buf, 1, 0, a4);
    rdB2(buf, 1, b3);
    if (j + 2 < 32) {
      stageUA(&As[buf][0], Abase + (j + 2) * 64, 0);
      stageUB(&Bs[buf][0], Bbase + (j + 2) * 64, 0);
    }
    __builtin_amdgcn_s_barrier();
    mmaP(a4, b3, 0);
    __builtin_amdgcn_s_barrier();

    rdA2(buf, 1, 1, a4);
    __builtin_amdgcn_s_barrier();
    mmaP(a4, b3, 4);
    if (j < 30)       asm volatile("s_waitcnt vmcnt(8) lgkmcnt(0)" ::: "memory");
    else if (j == 30) asm volatile("s_waitcnt vmcnt(4) lgkmcnt(0)" ::: "memory");
    else              asm volatile("s_waitcnt lgkmcnt(0)" ::: "memory");
    __builtin_amdgcn_s_barrier();
  }

#pragma unroll
  for (int mi = 0; mi < 8; mi++) {
    int rowb = m0 + wm * 128 + mi * 16 + l4 * 4;
    int b = rowb >> 11;
    int tok0 = rowb & 2047;
#pragma unroll
    for (int ni = 0; ni < 3; ni++) {
      int col = n0 + wn * 48 + ni * 16 + l15;
      int sec = col >> 11;
      int h = (col >> 7) & 15;
      int dh = col & 127;
      if (sec == 2) {
        u16x4 o;
#pragma unroll
        for (int r = 0; r < 4; r++) o[r] = f2bf(acc[mi][ni][r]);
        *(u16x4*)&vt[((size_t)(b * 16 + h) * 128 + dh) * 2048 + tok0] = o;
      } else {
        unsigned short* dst = (sec == 0) ? qb : kb;
        int dh2 = dh >> 1;
        int odd = dh & 1;
#pragma unroll
        for (int r = 0; r < 4; r++) {
          float v = acc[mi][ni][r];
          float p = __shfl_xor(v, 1, 64);
          float2 cs = *(const float2*)&freqs[((size_t)(tok0 + r) * 64 + dh2) * 2];
          float o = odd ? (v * cs.x + p * cs.y) : (v * cs.x - p * cs.y);
          dst[((size_t)(b * 16 + h) * 2048 + tok0 + r) * 128 + dh] = f2bf(o);
        }
      }
    }
  }
}

// --------------------- 128^2 GEMM (out-proj), naive/high-occupancy ------
__global__ __launch_bounds__(256) void k_gemm_out(
    const unsigned short* __restrict__ A,
    const unsigned short* __restrict__ Bt,
    int Kdim, int Nn,
    float* __restrict__ Cout) {
  __shared__ unsigned short As[128 * 64];
  __shared__ unsigned short Bs[128 * 64];
  const int t = threadIdx.x;
  const int lane = t & 63, wid = t >> 6;
  const int l15 = lane & 15, l4 = lane >> 4;
  const int m0 = blockIdx.y * 128, n0 = blockIdx.x * 128;
  const int wr = (wid >> 1) * 64, wc = (wid & 1) * 64;

  f32x4 acc[4][4];
#pragma unroll
  for (int i = 0; i < 4; i++)
#pragma unroll
    for (int j = 0; j < 4; j++) acc[i][j] = (f32x4)0.f;

  for (int k0 = 0; k0 < Kdim; k0 += 64) {
    __syncthreads();
#pragma unroll
    for (int j = 0; j < 4; j++) {
      int slotbase = j * 256 + wid * 64;
      int slot = slotbase + lane;
      int row = slot >> 3, cc = slot & 7;
      int cg = cc ^ (row & 7);
      gload_lds16(A + (size_t)(m0 + row) * Kdim + k0 + cg * 8, &As[slotbase * 8]);
      gload_lds16(Bt + (size_t)(n0 + row) * Kdim + k0 + cg * 8, &Bs[slotbase * 8]);
    }
    __syncthreads();
#pragma unroll
    for (int kk = 0; kk < 2; kk++) {
      bf16x8 af[4], bfr[4];
#pragma unroll
      for (int mi = 0; mi < 4; mi++) {
        int row = wr + mi * 16 + l15;
        int c = (kk * 4 + l4) ^ (row & 7);
        af[mi] = *(const bf16x8*)&As[row * 64 + c * 8];
      }
#pragma unroll
      for (int ni = 0; ni < 4; ni++) {
        int row = wc + ni * 16 + l15;
        int c = (kk * 4 + l4) ^ (row & 7);
        bfr[ni] = *(const bf16x8*)&Bs[row * 64 + c * 8];
      }
#pragma unroll
      for (int mi = 0; mi < 4; mi++)
#pragma unroll
        for (int ni = 0; ni < 4; ni++)
          acc[mi][ni] = __builtin_amdgcn_mfma_f32_16x16x32_bf16(af[mi], bfr[ni],
                                                                acc[mi][ni], 0, 0, 0);
    }
  }

#pragma unroll
  for (int mi = 0; mi < 4; mi++) {
    int rowb = m0 + wr + mi * 16 + l4 * 4;
#pragma unroll
    for (int ni = 0; ni < 4; ni++) {
      int col = n0 + wc + ni * 16 + l15;
#pragma unroll
      for (int r = 0; r < 4; r++)
        Cout[(size_t)(rowb + r) * Nn + col] = acc[mi][ni][r];
    }
  }
}

// ----------------------------------------------------------- attention ----
// ROUND-14: V staging DROPPED (guide common-mistake #7 / m169 precedent):
// every wave read the full 16KB V-tile from LDS anyway (4x duplication), so
// staging only bought L2->LDS caching at the cost of 32KB LDS and half the
// STAGE loads. Direct-global vf is address-identical (XOR swizzle cancels:
// staged read resolved to vbase[row*2048 + kv0 + kk*32 + l4*8]). LDS 80->48KB
// -> 3 blocks/CU (+50% TLP — the lever that won rounds 10/11/12). K stays
// staged/double-buffered (once per block, not per wave).
__global__ __launch_bounds__(256, 3) void k_attn(
    const unsigned short* __restrict__ qb,
    const unsigned short* __restrict__ kb,
    const unsigned short* __restrict__ vt,
    unsigned short* __restrict__ ao) {
  __shared__ unsigned short Ks[2][64 * 128];  // [kv][d], 16B-chunk XOR swizzled
  __shared__ unsigned short Ps[4][32 * 64];   // per-wave P scratch, swizzled
  const int t = threadIdx.x;
  const int lane = t & 63, wid = t >> 6;
  const int l15 = lane & 15, l4 = lane >> 4;
  const int qt0 = blockIdx.x * 128;
  const int bh = blockIdx.y;
  const unsigned short* qbase = qb + (size_t)bh * 2048 * 128;
  const unsigned short* kbase = kb + (size_t)bh * 2048 * 128;
  const unsigned short* vbase = vt + (size_t)bh * 128 * 2048;

  bf16x8 qf[2][4];
#pragma unroll
  for (int mi = 0; mi < 2; mi++) {
    int qrow = qt0 + wid * 32 + mi * 16 + l15;
#pragma unroll
    for (int dk = 0; dk < 4; dk++)
      qf[mi][dk] = *(const bf16x8*)&qbase[(size_t)qrow * 128 + dk * 32 + l4 * 8];
  }

  f32x4 O[2][8];
#pragma unroll
  for (int mi = 0; mi < 2; mi++)
#pragma unroll
    for (int df = 0; df < 8; df++) O[mi][df] = (f32x4)0.f;
  float lsum[2][4];
#pragma unroll
  for (int mi = 0; mi < 2; mi++)
#pragma unroll
    for (int r = 0; r < 4; r++) lsum[mi][r] = 0.f;

  const float scale = 0.08838834764831845f;  // 1/sqrt(128)

  // stage K only: 4 loads/thread
  auto STAGE = [&](int kv0, int buf) {
#pragma unroll
    for (int j = 0; j < 4; j++) {
      int slotbase = j * 256 + wid * 64;
      int slot = slotbase + lane;
      int rowk = slot >> 4, ck = slot & 15;
      gload_lds16(&kbase[(size_t)(kv0 + rowk) * 128 + (ck ^ (rowk & 7)) * 8],
                  &Ks[buf][slotbase * 8]);
    }
  };

  STAGE(0, 0);
  __syncthreads();

  for (int ti = 0; ti < 32; ti++) {
    const int cur = ti & 1;
    const int kv0 = ti * 64;
    if (ti < 31) STAGE((ti + 1) * 64, cur ^ 1);  // prefetch next K tile

    // S = Q K^T  (per wave 32x64, 2 m-frags)
    f32x4 s[2][4];
#pragma unroll
    for (int mi = 0; mi < 2; mi++)
#pragma unroll
      for (int ni = 0; ni < 4; ni++) s[mi][ni] = (f32x4)0.f;
#pragma unroll
    for (int dk = 0; dk < 4; dk++) {
      bf16x8 kf[4];
#pragma unroll
      for (int ni = 0; ni < 4; ni++) {
        int row = ni * 16 + l15;
        int c = (dk * 4 + l4) ^ (row & 7);
        kf[ni] = *(const bf16x8*)&Ks[cur][row * 128 + c * 8];
      }
#pragma unroll
      for (int mi = 0; mi < 2; mi++)
#pragma unroll
        for (int ni = 0; ni < 4; ni++)
          s[mi][ni] = __builtin_amdgcn_mfma_f32_16x16x32_bf16(qf[mi][dk], kf[ni],
                                                              s[mi][ni], 0, 0, 0);
    }

    // P = exp(S*scale), accumulate per-lane denominators, P -> LDS (swz)
    unsigned short* pbase = &Ps[wid][0];
#pragma unroll
    for (int mi = 0; mi < 2; mi++)
#pragma unroll
      for (int ni = 0; ni < 4; ni++) {
        int col = ni * 16 + l15;
#pragma unroll
        for (int r = 0; r < 4; r++) {
          float p = __expf(s[mi][ni][r] * scale);
          lsum[mi][r] += p;
          int rowp = mi * 16 + l4 * 4 + r;
          pbase[rowp * 64 + (((col >> 3) ^ (rowp & 7)) << 3) + (col & 7)] = f2bf(p);
        }
      }

    bf16x8 pf[2][2];
#pragma unroll
    for (int mi = 0; mi < 2; mi++)
#pragma unroll
      for (int kk = 0; kk < 2; kk++) {
        int row = mi * 16 + l15;
        int c = (kk * 4 + l4) ^ (row & 7);
        pf[mi][kk] = *(const bf16x8*)&pbase[row * 64 + c * 8];
      }

    // O += P V  (V direct from global vt [d][tok] — L2-resident)
#pragma unroll
    for (int df = 0; df < 8; df++) {
      bf16x8 vf[2];
#pragma unroll
      for (int kk = 0; kk < 2; kk++) {
        int row = df * 16 + l15;
        vf[kk] = *(const bf16x8*)&vbase[(size_t)row * 2048 + kv0 + kk * 32 + l4 * 8];
      }
#pragma unroll
      for (int mi = 0; mi < 2; mi++)
#pragma unroll
        for (int kk = 0; kk < 2; kk++)
          O[mi][df] = __builtin_amdgcn_mfma_f32_16x16x32_bf16(pf[mi][kk], vf[kk],
                                                              O[mi][df], 0, 0, 0);
    }

    __syncthreads();  // drains K prefetch + guards Ks/Ps reuse
  }

  float inv[2][4];
#pragma unroll
  for (int mi = 0; mi < 2; mi++)
#pragma unroll
    for (int r = 0; r < 4; r++) {
      float v = lsum[mi][r];
      v += __shfl_xor(v, 1, 64);
      v += __shfl_xor(v, 2, 64);
      v += __shfl_xor(v, 4, 64);
      v += __shfl_xor(v, 8, 64);
      inv[mi][r] = 1.0f / v;
    }

  const int b = bh >> 4, h = bh & 15;
#pragma unroll
  for (int mi = 0; mi < 2; mi++)
#pragma unroll
    for (int df = 0; df < 8; df++)
#pragma unroll
      for (int r = 0; r < 4; r++) {
        int tok = qt0 + wid * 32 + mi * 16 + l4 * 4 + r;
        ao[((size_t)(b * 2048 + tok)) * 2048 + h * 128 + df * 16 + l15] =
            f2bf(O[mi][df][r] * inv[mi][r]);
      }
}

// -------------------------------------------------------------- launch ----
extern "C" void kernel_launch(void* const* d_in, const int* in_sizes, int n_in,
                              void* d_out, int out_size, void* d_ws, size_t ws_size,
                              hipStream_t stream) {
  const float* x     = (const float*)d_in[0];  // [2,2048,2048]
  const float* freqs = (const float*)d_in[1];  // [2048,64,2]
  const float* wqkv  = (const float*)d_in[2];  // [2048,6144]
  const float* wo    = (const float*)d_in[3];  // [2048,2048]
  float* out = (float*)d_out;                  // [4096,2048]

  char* ws = (char*)d_ws;
  unsigned short* xb    = (unsigned short*)(ws + 0);          // 16.78 MB
  unsigned short* wqkvT = (unsigned short*)(ws + 16777216);   // 25.17 MB
  unsigned short* woT   = (unsigned short*)(ws + 41943040);   // 8.39 MB
  unsigned short* qb    = (unsigned short*)(ws + 50331648);   // 16.78 MB
  unsigned short* kb    = (unsigned short*)(ws + 67108864);   // 16.78 MB
  unsigned short* vt    = (unsigned short*)(ws + 83886080);   // 16.78 MB
  unsigned short* ao    = (unsigned short*)(ws + 100663296);  // 16.78 MB

  k_convert<<<dim3(4096), dim3(256), 0, stream>>>(x, xb, 1048576);
  k_transpose_bf16<<<dim3(192, 64), dim3(256), 0, stream>>>(wqkv, wqkvT, 2048, 6144);
  k_transpose_bf16<<<dim3(64, 64), dim3(256), 0, stream>>>(wo, woT, 2048, 2048);

  // qkv = xb @ wqkvT^T, fused RoPE, scatter (256x192 tiles, 2 clean rounds)
  k_gemm_qkv<<<dim3(512), dim3(512), 0, stream>>>(xb, wqkvT, qb, kb, vt, freqs);

  k_attn<<<dim3(16, 32), dim3(256), 0, stream>>>(qb, kb, vt, ao);

  // out = ao @ woT^T (naive 128^2, high occupancy — best measured)
  k_gemm_out<<<dim3(16, 32), dim3(256), 0, stream>>>(ao, woT, 2048, 2048, out);
}

// Round 16
// 270.348 us; speedup vs baseline: 2.1615x; 2.1615x over previous
//
#include <hip/hip_runtime.h>
#include <hip/hip_bf16.h>
#include <stdint.h>

typedef __attribute__((ext_vector_type(8))) short bf16x8;
typedef __attribute__((ext_vector_type(4))) float f32x4;
typedef __attribute__((ext_vector_type(4))) unsigned short u16x4;
typedef __attribute__((ext_vector_type(8))) unsigned short u16x8;

#define DEV __device__ __forceinline__

DEV unsigned short f2bf(float f) {
  union { __hip_bfloat16 h; unsigned short u; } cv;
  cv.h = __float2bfloat16(f);
  return cv.u;
}

// global -> LDS direct load, 16B per lane. LDS dest is wave-uniform base;
// HW adds lane*16. Global src is per-lane.
DEV void gload_lds16(const void* g, void* l) {
  __builtin_amdgcn_global_load_lds(
      (__attribute__((address_space(1))) void*)(uintptr_t)g,
      (__attribute__((address_space(3))) void*)(uint32_t)(uintptr_t)l,
      16, 0, 0);
}

// ---------------------------------------------------------------- prep ----
__global__ __launch_bounds__(256) void k_convert(const float* __restrict__ in,
                                                 unsigned short* __restrict__ out,
                                                 int n8) {
  int i = blockIdx.x * 256 + threadIdx.x;
  if (i >= n8) return;
  const float4* p = (const float4*)in + (size_t)i * 2;
  float4 a = p[0], b = p[1];
  u16x8 o;
  o[0] = f2bf(a.x); o[1] = f2bf(a.y); o[2] = f2bf(a.z); o[3] = f2bf(a.w);
  o[4] = f2bf(b.x); o[5] = f2bf(b.y); o[6] = f2bf(b.z); o[7] = f2bf(b.w);
  *((u16x8*)out + (size_t)i) = o;
}

// in: [R][C] f32  ->  out: [C][R] bf16
__global__ __launch_bounds__(256) void k_transpose_bf16(const float* __restrict__ in,
                                                        unsigned short* __restrict__ out,
                                                        int R, int C) {
  __shared__ float tile[32][33];
  const int t = threadIdx.x;
  const int c0 = blockIdx.x * 32, r0 = blockIdx.y * 32;
  {
    int r = t >> 3, c4 = (t & 7) * 4;
    float4 v = *(const float4*)&in[(size_t)(r0 + r) * C + c0 + c4];
    tile[r][c4] = v.x; tile[r][c4 + 1] = v.y; tile[r][c4 + 2] = v.z; tile[r][c4 + 3] = v.w;
  }
  __syncthreads();
  int c = t >> 3, r4 = (t & 7) * 4;
  u16x4 o;
  o[0] = f2bf(tile[r4 + 0][c]); o[1] = f2bf(tile[r4 + 1][c]);
  o[2] = f2bf(tile[r4 + 2][c]); o[3] = f2bf(tile[r4 + 3][c]);
  *(u16x4*)&out[(size_t)(c0 + c) * R + r0 + r4] = o;
}

// -------------------------------------- 256x192 8-phase qkv GEMM (T4) ----
// (round-9 version — best measured of 7 schedule variants: 141.5us band)
__global__ __launch_bounds__(512, 2) void k_gemm_qkv(
    const unsigned short* __restrict__ A,
    const unsigned short* __restrict__ Bt,
    unsigned short* __restrict__ qb,
    unsigned short* __restrict__ kb,
    unsigned short* __restrict__ vt,
    const float* __restrict__ freqs) {
  constexpr int Kdim = 2048;
  __shared__ unsigned short As[2][16384];  // [buf][khalf*8192 + slot*8]
  __shared__ unsigned short Bs[2][12288];  // [buf][khalf*6144 + slot*8]
  const int t = threadIdx.x;
  const int lane = t & 63, wid = t >> 6;
  const int l15 = lane & 15, l4 = (lane >> 4) & 3;
  const int wm = wid >> 2, wn = wid & 3;
  const int bid = blockIdx.x;
  const int wg = (bid & 7) * 64 + (bid >> 3);
  const int by = wg & 15, bx = wg >> 4;  // by 0..15, bx 0..31
  const int m0 = by * 256, n0 = bx * 192;

  f32x4 acc[8][3];
#pragma unroll
  for (int i = 0; i < 8; i++)
#pragma unroll
    for (int j = 0; j < 3; j++) acc[i][j] = (f32x4)0.f;

  auto stageUA = [&](unsigned short* dstUnit, const unsigned short* src, int khalf) {
#pragma unroll
    for (int cb = 0; cb < 2; cb++) {
      int slotu = cb * 512 + wid * 64;
      int slot = slotu + lane;
      int row = slot >> 2, s = slot & 3;
      int c = s ^ ((row >> 1) & 3);
      gload_lds16(src + (size_t)row * Kdim + khalf * 32 + c * 8,
                  dstUnit + slotu * 8);
    }
  };
  auto stageUB = [&](unsigned short* dstUnit, const unsigned short* src, int khalf) {
    {
      int slotu = wid * 64;
      int slot = slotu + lane;
      int row = slot >> 2, s = slot & 3;
      int c = s ^ ((row >> 1) & 3);
      gload_lds16(src + (size_t)row * Kdim + khalf * 32 + c * 8,
                  dstUnit + slotu * 8);
    }
    {
      int slotu = 512 + (wid & 3) * 64;
      int slot = slotu + lane;
      int row = slot >> 2, s = slot & 3;
      int c = s ^ ((row >> 1) & 3);
      gload_lds16(src + (size_t)row * Kdim + khalf * 32 + c * 8,
                  dstUnit + slotu * 8);
    }
  };

  auto rdA2 = [&](int buf, int kk, int mh, bf16x8 (&f)[4]) {
    const unsigned short* base = &As[buf][kk * 8192];
#pragma unroll
    for (int mi = 0; mi < 4; mi++) {
      int row = wm * 128 + mh * 64 + mi * 16 + l15;
      int s = l4 ^ ((row >> 1) & 3);
      f[mi] = *(const bf16x8*)&base[row * 32 + s * 8];
    }
  };
  auto rdB2 = [&](int buf, int kk, bf16x8 (&f)[3]) {
    const unsigned short* base = &Bs[buf][kk * 6144];
#pragma unroll
    for (int ni = 0; ni < 3; ni++) {
      int row = wn * 48 + ni * 16 + l15;
      int s = l4 ^ ((row >> 1) & 3);
      f[ni] = *(const bf16x8*)&base[row * 32 + s * 8];
    }
  };
  auto mmaP = [&](bf16x8 (&a4)[4], bf16x8 (&b3)[3], int mib) {
    __builtin_amdgcn_s_setprio(1);
#pragma unroll
    for (int mi = 0; mi < 4; mi++)
#pragma unroll
      for (int ni = 0; ni < 3; ni++)
        acc[mib + mi][ni] = __builtin_amdgcn_mfma_f32_16x16x32_bf16(
            a4[mi], b3[ni], acc[mib + mi][ni], 0, 0, 0);
    __builtin_amdgcn_s_setprio(0);
  };

  const unsigned short* Abase = A + (size_t)m0 * Kdim;
  const unsigned short* Bbase = Bt + (size_t)n0 * Kdim;

  stageUA(&As[0][0], Abase, 0);
  stageUB(&Bs[0][0], Bbase, 0);
  stageUA(&As[0][8192], Abase, 1);
  stageUB(&Bs[0][6144], Bbase, 1);
  stageUA(&As[1][0], Abase + 64, 0);
  stageUB(&Bs[1][0], Bbase + 64, 0);
  asm volatile("s_waitcnt vmcnt(8)" ::: "memory");
  __builtin_amdgcn_s_barrier();

  bf16x8 a4[4], b3[3];
  for (int j = 0; j < 32; j++) {
    const int buf = j & 1;

    rdA2(buf, 0, 0, a4);
    rdB2(buf, 0, b3);
    if (j + 1 < 32) {
      stageUA(&As[buf ^ 1][8192], Abase + (j + 1) * 64, 1);
      stageUB(&Bs[buf ^ 1][6144], Bbase + (j + 1) * 64, 1);
    }
    __builtin_amdgcn_s_barrier();
    mmaP(a4, b3, 0);
    __builtin_amdgcn_s_barrier();

    rdA2(buf, 0, 1, a4);
    __builtin_amdgcn_s_barrier();
    mmaP(a4, b3, 4);
    if (j < 31) asm volatile("s_waitcnt vmcnt(8) lgkmcnt(0)" ::: "memory");
    else        asm volatile("s_waitcnt vmcnt(0) lgkmcnt(0)" ::: "memory");
    __builtin_amdgcn_s_barrier();

    rdA2(buf, 1, 0, a4);
    rdB2(buf, 1, b3);
    if (j + 2 < 32) {
      stageUA(&As[buf][0], Abase + (j + 2) * 64, 0);
      stageUB(&Bs[buf][0], Bbase + (j + 2) * 64, 0);
    }
    __builtin_amdgcn_s_barrier();
    mmaP(a4, b3, 0);
    __builtin_amdgcn_s_barrier();

    rdA2(buf, 1, 1, a4);
    __builtin_amdgcn_s_barrier();
    mmaP(a4, b3, 4);
    if (j < 30)       asm volatile("s_waitcnt vmcnt(8) lgkmcnt(0)" ::: "memory");
    else if (j == 30) asm volatile("s_waitcnt vmcnt(4) lgkmcnt(0)" ::: "memory");
    else              asm volatile("s_waitcnt lgkmcnt(0)" ::: "memory");
    __builtin_amdgcn_s_barrier();
  }

#pragma unroll
  for (int mi = 0; mi < 8; mi++) {
    int rowb = m0 + wm * 128 + mi * 16 + l4 * 4;
    int b = rowb >> 11;
    int tok0 = rowb & 2047;
#pragma unroll
    for (int ni = 0; ni < 3; ni++) {
      int col = n0 + wn * 48 + ni * 16 + l15;
      int sec = col >> 11;
      int h = (col >> 7) & 15;
      int dh = col & 127;
      if (sec == 2) {
        u16x4 o;
#pragma unroll
        for (int r = 0; r < 4; r++) o[r] = f2bf(acc[mi][ni][r]);
        *(u16x4*)&vt[((size_t)(b * 16 + h) * 128 + dh) * 2048 + tok0] = o;
      } else {
        unsigned short* dst = (sec == 0) ? qb : kb;
        int dh2 = dh >> 1;
        int odd = dh & 1;
#pragma unroll
        for (int r = 0; r < 4; r++) {
          float v = acc[mi][ni][r];
          float p = __shfl_xor(v, 1, 64);
          float2 cs = *(const float2*)&freqs[((size_t)(tok0 + r) * 64 + dh2) * 2];
          float o = odd ? (v * cs.x + p * cs.y) : (v * cs.x - p * cs.y);
          dst[((size_t)(b * 16 + h) * 2048 + tok0 + r) * 128 + dh] = f2bf(o);
        }
      }
    }
  }
}

// --------------------- 128^2 GEMM (out-proj), naive/high-occupancy ------
__global__ __launch_bounds__(256) void k_gemm_out(
    const unsigned short* __restrict__ A,
    const unsigned short* __restrict__ Bt,
    int Kdim, int Nn,
    float* __restrict__ Cout) {
  __shared__ unsigned short As[128 * 64];
  __shared__ unsigned short Bs[128 * 64];
  const int t = threadIdx.x;
  const int lane = t & 63, wid = t >> 6;
  const int l15 = lane & 15, l4 = lane >> 4;
  const int m0 = blockIdx.y * 128, n0 = blockIdx.x * 128;
  const int wr = (wid >> 1) * 64, wc = (wid & 1) * 64;

  f32x4 acc[4][4];
#pragma unroll
  for (int i = 0; i < 4; i++)
#pragma unroll
    for (int j = 0; j < 4; j++) acc[i][j] = (f32x4)0.f;

  for (int k0 = 0; k0 < Kdim; k0 += 64) {
    __syncthreads();
#pragma unroll
    for (int j = 0; j < 4; j++) {
      int slotbase = j * 256 + wid * 64;
      int slot = slotbase + lane;
      int row = slot >> 3, cc = slot & 7;
      int cg = cc ^ (row & 7);
      gload_lds16(A + (size_t)(m0 + row) * Kdim + k0 + cg * 8, &As[slotbase * 8]);
      gload_lds16(Bt + (size_t)(n0 + row) * Kdim + k0 + cg * 8, &Bs[slotbase * 8]);
    }
    __syncthreads();
#pragma unroll
    for (int kk = 0; kk < 2; kk++) {
      bf16x8 af[4], bfr[4];
#pragma unroll
      for (int mi = 0; mi < 4; mi++) {
        int row = wr + mi * 16 + l15;
        int c = (kk * 4 + l4) ^ (row & 7);
        af[mi] = *(const bf16x8*)&As[row * 64 + c * 8];
      }
#pragma unroll
      for (int ni = 0; ni < 4; ni++) {
        int row = wc + ni * 16 + l15;
        int c = (kk * 4 + l4) ^ (row & 7);
        bfr[ni] = *(const bf16x8*)&Bs[row * 64 + c * 8];
      }
#pragma unroll
      for (int mi = 0; mi < 4; mi++)
#pragma unroll
        for (int ni = 0; ni < 4; ni++)
          acc[mi][ni] = __builtin_amdgcn_mfma_f32_16x16x32_bf16(af[mi], bfr[ni],
                                                                acc[mi][ni], 0, 0, 0);
    }
  }

#pragma unroll
  for (int mi = 0; mi < 4; mi++) {
    int rowb = m0 + wr + mi * 16 + l4 * 4;
#pragma unroll
    for (int ni = 0; ni < 4; ni++) {
      int col = n0 + wc + ni * 16 + l15;
#pragma unroll
      for (int r = 0; r < 4; r++)
        Cout[(size_t)(rowb + r) * Nn + col] = acc[mi][ni][r];
    }
  }
}

// ----------------------------------------------------------- attention ----
// (round-9/13 version — best measured: QBLK=128, 4 waves x 32 q-rows, KV
// tile 64 double-buffered K AND V staging, 2 blocks/CU. V staging is
// load-bearing: round-14's direct-global V read was 5.4x slower — the
// staged global_load_lds pass is coalesced + once-per-block, while PV's
// fragment pattern scatters 16B reads across 4KB-strided rows.)
__global__ __launch_bounds__(256, 2) void k_attn(
    const unsigned short* __restrict__ qb,
    const unsigned short* __restrict__ kb,
    const unsigned short* __restrict__ vt,
    unsigned short* __restrict__ ao) {
  __shared__ unsigned short Ks[2][64 * 128];  // [kv][d], 16B-chunk XOR swizzled
  __shared__ unsigned short Vs[2][64 * 128];  // [d][kv], swizzled
  __shared__ unsigned short Ps[4][32 * 64];   // per-wave P scratch, swizzled
  const int t = threadIdx.x;
  const int lane = t & 63, wid = t >> 6;
  const int l15 = lane & 15, l4 = lane >> 4;
  const int qt0 = blockIdx.x * 128;
  const int bh = blockIdx.y;
  const unsigned short* qbase = qb + (size_t)bh * 2048 * 128;
  const unsigned short* kbase = kb + (size_t)bh * 2048 * 128;
  const unsigned short* vbase = vt + (size_t)bh * 128 * 2048;

  bf16x8 qf[2][4];
#pragma unroll
  for (int mi = 0; mi < 2; mi++) {
    int qrow = qt0 + wid * 32 + mi * 16 + l15;
#pragma unroll
    for (int dk = 0; dk < 4; dk++)
      qf[mi][dk] = *(const bf16x8*)&qbase[(size_t)qrow * 128 + dk * 32 + l4 * 8];
  }

  f32x4 O[2][8];
#pragma unroll
  for (int mi = 0; mi < 2; mi++)
#pragma unroll
    for (int df = 0; df < 8; df++) O[mi][df] = (f32x4)0.f;
  float lsum[2][4];
#pragma unroll
  for (int mi = 0; mi < 2; mi++)
#pragma unroll
    for (int r = 0; r < 4; r++) lsum[mi][r] = 0.f;

  const float scale = 0.08838834764831845f;  // 1/sqrt(128)

  auto STAGE = [&](int kv0, int buf) {
#pragma unroll
    for (int j = 0; j < 4; j++) {
      int slotbase = j * 256 + wid * 64;
      int slot = slotbase + lane;
      int rowk = slot >> 4, ck = slot & 15;
      gload_lds16(&kbase[(size_t)(kv0 + rowk) * 128 + (ck ^ (rowk & 7)) * 8],
                  &Ks[buf][slotbase * 8]);
      int rowv = slot >> 3, cv = slot & 7;
      gload_lds16(&vbase[(size_t)rowv * 2048 + kv0 + (cv ^ (rowv & 7)) * 8],
                  &Vs[buf][slotbase * 8]);
    }
  };

  STAGE(0, 0);
  __syncthreads();

  for (int ti = 0; ti < 32; ti++) {
    const int cur = ti & 1;
    if (ti < 31) STAGE((ti + 1) * 64, cur ^ 1);  // prefetch next tile

    f32x4 s[2][4];
#pragma unroll
    for (int mi = 0; mi < 2; mi++)
#pragma unroll
      for (int ni = 0; ni < 4; ni++) s[mi][ni] = (f32x4)0.f;
#pragma unroll
    for (int dk = 0; dk < 4; dk++) {
      bf16x8 kf[4];
#pragma unroll
      for (int ni = 0; ni < 4; ni++) {
        int row = ni * 16 + l15;
        int c = (dk * 4 + l4) ^ (row & 7);
        kf[ni] = *(const bf16x8*)&Ks[cur][row * 128 + c * 8];
      }
#pragma unroll
      for (int mi = 0; mi < 2; mi++)
#pragma unroll
        for (int ni = 0; ni < 4; ni++)
          s[mi][ni] = __builtin_amdgcn_mfma_f32_16x16x32_bf16(qf[mi][dk], kf[ni],
                                                              s[mi][ni], 0, 0, 0);
    }

    unsigned short* pbase = &Ps[wid][0];
#pragma unroll
    for (int mi = 0; mi < 2; mi++)
#pragma unroll
      for (int ni = 0; ni < 4; ni++) {
        int col = ni * 16 + l15;
#pragma unroll
        for (int r = 0; r < 4; r++) {
          float p = __expf(s[mi][ni][r] * scale);
          lsum[mi][r] += p;
          int rowp = mi * 16 + l4 * 4 + r;
          pbase[rowp * 64 + (((col >> 3) ^ (rowp & 7)) << 3) + (col & 7)] = f2bf(p);
        }
      }

    bf16x8 pf[2][2];
#pragma unroll
    for (int mi = 0; mi < 2; mi++)
#pragma unroll
      for (int kk = 0; kk < 2; kk++) {
        int row = mi * 16 + l15;
        int c = (kk * 4 + l4) ^ (row & 7);
        pf[mi][kk] = *(const bf16x8*)&pbase[row * 64 + c * 8];
      }

#pragma unroll
    for (int df = 0; df < 8; df++) {
      bf16x8 vf[2];
#pragma unroll
      for (int kk = 0; kk < 2; kk++) {
        int row = df * 16 + l15;
        int c = (kk * 4 + l4) ^ (row & 7);
        vf[kk] = *(const bf16x8*)&Vs[cur][row * 64 + c * 8];
      }
#pragma unroll
      for (int mi = 0; mi < 2; mi++)
#pragma unroll
        for (int kk = 0; kk < 2; kk++)
          O[mi][df] = __builtin_amdgcn_mfma_f32_16x16x32_bf16(pf[mi][kk], vf[kk],
                                                              O[mi][df], 0, 0, 0);
    }

    __syncthreads();  // drains prefetch (vmcnt) + guards buffer reuse
  }

  float inv[2][4];
#pragma unroll
  for (int mi = 0; mi < 2; mi++)
#pragma unroll
    for (int r = 0; r < 4; r++) {
      float v = lsum[mi][r];
      v += __shfl_xor(v, 1, 64);
      v += __shfl_xor(v, 2, 64);
      v += __shfl_xor(v, 4, 64);
      v += __shfl_xor(v, 8, 64);
      inv[mi][r] = 1.0f / v;
    }

  const int b = bh >> 4, h = bh & 15;
#pragma unroll
  for (int mi = 0; mi < 2; mi++)
#pragma unroll
    for (int df = 0; df < 8; df++)
#pragma unroll
      for (int r = 0; r < 4; r++) {
        int tok = qt0 + wid * 32 + mi * 16 + l4 * 4 + r;
        ao[((size_t)(b * 2048 + tok)) * 2048 + h * 128 + df * 16 + l15] =
            f2bf(O[mi][df][r] * inv[mi][r]);
      }
}

// -------------------------------------------------------------- launch ----
extern "C" void kernel_launch(void* const* d_in, const int* in_sizes, int n_in,
                              void* d_out, int out_size, void* d_ws, size_t ws_size,
                              hipStream_t stream) {
  const float* x     = (const float*)d_in[0];  // [2,2048,2048]
  const float* freqs = (const float*)d_in[1];  // [2048,64,2]
  const float* wqkv  = (const float*)d_in[2];  // [2048,6144]
  const float* wo    = (const float*)d_in[3];  // [2048,2048]
  float* out = (float*)d_out;                  // [4096,2048]

  char* ws = (char*)d_ws;
  unsigned short* xb    = (unsigned short*)(ws + 0);          // 16.78 MB
  unsigned short* wqkvT = (unsigned short*)(ws + 16777216);   // 25.17 MB
  unsigned short* woT   = (unsigned short*)(ws + 41943040);   // 8.39 MB
  unsigned short* qb    = (unsigned short*)(ws + 50331648);   // 16.78 MB
  unsigned short* kb    = (unsigned short*)(ws + 67108864);   // 16.78 MB
  unsigned short* vt    = (unsigned short*)(ws + 83886080);   // 16.78 MB
  unsigned short* ao    = (unsigned short*)(ws + 100663296);  // 16.78 MB

  k_convert<<<dim3(4096), dim3(256), 0, stream>>>(x, xb, 1048576);
  k_transpose_bf16<<<dim3(192, 64), dim3(256), 0, stream>>>(wqkv, wqkvT, 2048, 6144);
  k_transpose_bf16<<<dim3(64, 64), dim3(256), 0, stream>>>(wo, woT, 2048, 2048);

  // qkv = xb @ wqkvT^T, fused RoPE, scatter (256x192 tiles, 2 clean rounds)
  k_gemm_qkv<<<dim3(512), dim3(512), 0, stream>>>(xb, wqkvT, qb, kb, vt, freqs);

  k_attn<<<dim3(16, 32), dim3(256), 0, stream>>>(qb, kb, vt, ao);

  // out = ao @ woT^T (naive 128^2, high occupancy — best measured)
  k_gemm_out<<<dim3(16, 32), dim3(256), 0, stream>>>(ao, woT, 2048, 2048, out);
}

// Round 17
// 267.253 us; speedup vs baseline: 2.1865x; 1.0116x over previous
//
#include <hip/hip_runtime.h>
#include <hip/hip_bf16.h>
#include <stdint.h>

typedef __attribute__((ext_vector_type(8))) short bf16x8;
typedef __attribute__((ext_vector_type(4))) float f32x4;
typedef __attribute__((ext_vector_type(4))) unsigned short u16x4;
typedef __attribute__((ext_vector_type(8))) unsigned short u16x8;

#define DEV __device__ __forceinline__

DEV unsigned short f2bf(float f) {
  union { __hip_bfloat16 h; unsigned short u; } cv;
  cv.h = __float2bfloat16(f);
  return cv.u;
}

// global -> LDS direct load, 16B per lane. LDS dest is wave-uniform base;
// HW adds lane*16. Global src is per-lane.
DEV void gload_lds16(const void* g, void* l) {
  __builtin_amdgcn_global_load_lds(
      (__attribute__((address_space(1))) void*)(uintptr_t)g,
      (__attribute__((address_space(3))) void*)(uint32_t)(uintptr_t)l,
      16, 0, 0);
}

// ---------------------------------------------------------------- prep ----
// ROUND-17: fused single-launch prep (convert + 2 transposes). The three
// kernels have no mutual deps; fusing removes 2 full-GPU drain bubbles +
// launch gaps. Block ranges: [0,4096) convert x->xb; [4096,16384) transpose
// wqkv [2048][6144] -> wqkvT; [16384,20480) transpose wo [2048][2048] -> woT.
__global__ __launch_bounds__(256) void k_prep(
    const float* __restrict__ x, unsigned short* __restrict__ xb,
    const float* __restrict__ wqkv, unsigned short* __restrict__ wqkvT,
    const float* __restrict__ wo, unsigned short* __restrict__ woT) {
  __shared__ float tile[32][33];
  const int bid = blockIdx.x;
  const int t = threadIdx.x;

  if (bid < 4096) {
    // convert: 4096*256 threads cover exactly 1048576 x8 chunks
    int i = bid * 256 + t;
    const float4* p = (const float4*)x + (size_t)i * 2;
    float4 a = p[0], b = p[1];
    u16x8 o;
    o[0] = f2bf(a.x); o[1] = f2bf(a.y); o[2] = f2bf(a.z); o[3] = f2bf(a.w);
    o[4] = f2bf(b.x); o[5] = f2bf(b.y); o[6] = f2bf(b.z); o[7] = f2bf(b.w);
    *((u16x8*)xb + (size_t)i) = o;
    return;
  }

  const float* in;
  unsigned short* out;
  int R, C, c0, r0;
  if (bid < 16384) {
    int idx = bid - 4096;
    in = wqkv; out = wqkvT; R = 2048; C = 6144;
    c0 = (idx % 192) * 32; r0 = (idx / 192) * 32;
  } else {
    int idx = bid - 16384;
    in = wo; out = woT; R = 2048; C = 2048;
    c0 = (idx & 63) * 32; r0 = (idx >> 6) * 32;
  }
  {
    int r = t >> 3, c4 = (t & 7) * 4;
    float4 v = *(const float4*)&in[(size_t)(r0 + r) * C + c0 + c4];
    tile[r][c4] = v.x; tile[r][c4 + 1] = v.y; tile[r][c4 + 2] = v.z; tile[r][c4 + 3] = v.w;
  }
  __syncthreads();
  int c = t >> 3, r4 = (t & 7) * 4;
  u16x4 o;
  o[0] = f2bf(tile[r4 + 0][c]); o[1] = f2bf(tile[r4 + 1][c]);
  o[2] = f2bf(tile[r4 + 2][c]); o[3] = f2bf(tile[r4 + 3][c]);
  *(u16x4*)&out[(size_t)(c0 + c) * R + r0 + r4] = o;
}

// -------------------------------------- 256x192 8-phase qkv GEMM (T4) ----
// (round-9 version — best measured of 7 schedule variants: 141.5us band)
__global__ __launch_bounds__(512, 2) void k_gemm_qkv(
    const unsigned short* __restrict__ A,
    const unsigned short* __restrict__ Bt,
    unsigned short* __restrict__ qb,
    unsigned short* __restrict__ kb,
    unsigned short* __restrict__ vt,
    const float* __restrict__ freqs) {
  constexpr int Kdim = 2048;
  __shared__ unsigned short As[2][16384];  // [buf][khalf*8192 + slot*8]
  __shared__ unsigned short Bs[2][12288];  // [buf][khalf*6144 + slot*8]
  const int t = threadIdx.x;
  const int lane = t & 63, wid = t >> 6;
  const int l15 = lane & 15, l4 = (lane >> 4) & 3;
  const int wm = wid >> 2, wn = wid & 3;
  const int bid = blockIdx.x;
  const int wg = (bid & 7) * 64 + (bid >> 3);
  const int by = wg & 15, bx = wg >> 4;  // by 0..15, bx 0..31
  const int m0 = by * 256, n0 = bx * 192;

  f32x4 acc[8][3];
#pragma unroll
  for (int i = 0; i < 8; i++)
#pragma unroll
    for (int j = 0; j < 3; j++) acc[i][j] = (f32x4)0.f;

  auto stageUA = [&](unsigned short* dstUnit, const unsigned short* src, int khalf) {
#pragma unroll
    for (int cb = 0; cb < 2; cb++) {
      int slotu = cb * 512 + wid * 64;
      int slot = slotu + lane;
      int row = slot >> 2, s = slot & 3;
      int c = s ^ ((row >> 1) & 3);
      gload_lds16(src + (size_t)row * Kdim + khalf * 32 + c * 8,
                  dstUnit + slotu * 8);
    }
  };
  auto stageUB = [&](unsigned short* dstUnit, const unsigned short* src, int khalf) {
    {
      int slotu = wid * 64;
      int slot = slotu + lane;
      int row = slot >> 2, s = slot & 3;
      int c = s ^ ((row >> 1) & 3);
      gload_lds16(src + (size_t)row * Kdim + khalf * 32 + c * 8,
                  dstUnit + slotu * 8);
    }
    {
      int slotu = 512 + (wid & 3) * 64;
      int slot = slotu + lane;
      int row = slot >> 2, s = slot & 3;
      int c = s ^ ((row >> 1) & 3);
      gload_lds16(src + (size_t)row * Kdim + khalf * 32 + c * 8,
                  dstUnit + slotu * 8);
    }
  };

  auto rdA2 = [&](int buf, int kk, int mh, bf16x8 (&f)[4]) {
    const unsigned short* base = &As[buf][kk * 8192];
#pragma unroll
    for (int mi = 0; mi < 4; mi++) {
      int row = wm * 128 + mh * 64 + mi * 16 + l15;
      int s = l4 ^ ((row >> 1) & 3);
      f[mi] = *(const bf16x8*)&base[row * 32 + s * 8];
    }
  };
  auto rdB2 = [&](int buf, int kk, bf16x8 (&f)[3]) {
    const unsigned short* base = &Bs[buf][kk * 6144];
#pragma unroll
    for (int ni = 0; ni < 3; ni++) {
      int row = wn * 48 + ni * 16 + l15;
      int s = l4 ^ ((row >> 1) & 3);
      f[ni] = *(const bf16x8*)&base[row * 32 + s * 8];
    }
  };
  auto mmaP = [&](bf16x8 (&a4)[4], bf16x8 (&b3)[3], int mib) {
    __builtin_amdgcn_s_setprio(1);
#pragma unroll
    for (int mi = 0; mi < 4; mi++)
#pragma unroll
      for (int ni = 0; ni < 3; ni++)
        acc[mib + mi][ni] = __builtin_amdgcn_mfma_f32_16x16x32_bf16(
            a4[mi], b3[ni], acc[mib + mi][ni], 0, 0, 0);
    __builtin_amdgcn_s_setprio(0);
  };

  const unsigned short* Abase = A + (size_t)m0 * Kdim;
  const unsigned short* Bbase = Bt + (size_t)n0 * Kdim;

  stageUA(&As[0][0], Abase, 0);
  stageUB(&Bs[0][0], Bbase, 0);
  stageUA(&As[0][8192], Abase, 1);
  stageUB(&Bs[0][6144], Bbase, 1);
  stageUA(&As[1][0], Abase + 64, 0);
  stageUB(&Bs[1][0], Bbase + 64, 0);
  asm volatile("s_waitcnt vmcnt(8)" ::: "memory");
  __builtin_amdgcn_s_barrier();

  bf16x8 a4[4], b3[3];
  for (int j = 0; j < 32; j++) {
    const int buf = j & 1;

    rdA2(buf, 0, 0, a4);
    rdB2(buf, 0, b3);
    if (j + 1 < 32) {
      stageUA(&As[buf ^ 1][8192], Abase + (j + 1) * 64, 1);
      stageUB(&Bs[buf ^ 1][6144], Bbase + (j + 1) * 64, 1);
    }
    __builtin_amdgcn_s_barrier();
    mmaP(a4, b3, 0);
    __builtin_amdgcn_s_barrier();

    rdA2(buf, 0, 1, a4);
    __builtin_amdgcn_s_barrier();
    mmaP(a4, b3, 4);
    if (j < 31) asm volatile("s_waitcnt vmcnt(8) lgkmcnt(0)" ::: "memory");
    else        asm volatile("s_waitcnt vmcnt(0) lgkmcnt(0)" ::: "memory");
    __builtin_amdgcn_s_barrier();

    rdA2(buf, 1, 0, a4);
    rdB2(buf, 1, b3);
    if (j + 2 < 32) {
      stageUA(&As[buf][0], Abase + (j + 2) * 64, 0);
      stageUB(&Bs[buf][0], Bbase + (j + 2) * 64, 0);
    }
    __builtin_amdgcn_s_barrier();
    mmaP(a4, b3, 0);
    __builtin_amdgcn_s_barrier();

    rdA2(buf, 1, 1, a4);
    __builtin_amdgcn_s_barrier();
    mmaP(a4, b3, 4);
    if (j < 30)       asm volatile("s_waitcnt vmcnt(8) lgkmcnt(0)" ::: "memory");
    else if (j == 30) asm volatile("s_waitcnt vmcnt(4) lgkmcnt(0)" ::: "memory");
    else              asm volatile("s_waitcnt lgkmcnt(0)" ::: "memory");
    __builtin_amdgcn_s_barrier();
  }

#pragma unroll
  for (int mi = 0; mi < 8; mi++) {
    int rowb = m0 + wm * 128 + mi * 16 + l4 * 4;
    int b = rowb >> 11;
    int tok0 = rowb & 2047;
#pragma unroll
    for (int ni = 0; ni < 3; ni++) {
      int col = n0 + wn * 48 + ni * 16 + l15;
      int sec = col >> 11;
      int h = (col >> 7) & 15;
      int dh = col & 127;
      if (sec == 2) {
        u16x4 o;
#pragma unroll
        for (int r = 0; r < 4; r++) o[r] = f2bf(acc[mi][ni][r]);
        *(u16x4*)&vt[((size_t)(b * 16 + h) * 128 + dh) * 2048 + tok0] = o;
      } else {
        unsigned short* dst = (sec == 0) ? qb : kb;
        int dh2 = dh >> 1;
        int odd = dh & 1;
#pragma unroll
        for (int r = 0; r < 4; r++) {
          float v = acc[mi][ni][r];
          float p = __shfl_xor(v, 1, 64);
          float2 cs = *(const float2*)&freqs[((size_t)(tok0 + r) * 64 + dh2) * 2];
          float o = odd ? (v * cs.x + p * cs.y) : (v * cs.x - p * cs.y);
          dst[((size_t)(b * 16 + h) * 2048 + tok0 + r) * 128 + dh] = f2bf(o);
        }
      }
    }
  }
}

// --------------------- 128^2 GEMM (out-proj), naive/high-occupancy ------
__global__ __launch_bounds__(256) void k_gemm_out(
    const unsigned short* __restrict__ A,
    const unsigned short* __restrict__ Bt,
    int Kdim, int Nn,
    float* __restrict__ Cout) {
  __shared__ unsigned short As[128 * 64];
  __shared__ unsigned short Bs[128 * 64];
  const int t = threadIdx.x;
  const int lane = t & 63, wid = t >> 6;
  const int l15 = lane & 15, l4 = lane >> 4;
  const int m0 = blockIdx.y * 128, n0 = blockIdx.x * 128;
  const int wr = (wid >> 1) * 64, wc = (wid & 1) * 64;

  f32x4 acc[4][4];
#pragma unroll
  for (int i = 0; i < 4; i++)
#pragma unroll
    for (int j = 0; j < 4; j++) acc[i][j] = (f32x4)0.f;

  for (int k0 = 0; k0 < Kdim; k0 += 64) {
    __syncthreads();
#pragma unroll
    for (int j = 0; j < 4; j++) {
      int slotbase = j * 256 + wid * 64;
      int slot = slotbase + lane;
      int row = slot >> 3, cc = slot & 7;
      int cg = cc ^ (row & 7);
      gload_lds16(A + (size_t)(m0 + row) * Kdim + k0 + cg * 8, &As[slotbase * 8]);
      gload_lds16(Bt + (size_t)(n0 + row) * Kdim + k0 + cg * 8, &Bs[slotbase * 8]);
    }
    __syncthreads();
#pragma unroll
    for (int kk = 0; kk < 2; kk++) {
      bf16x8 af[4], bfr[4];
#pragma unroll
      for (int mi = 0; mi < 4; mi++) {
        int row = wr + mi * 16 + l15;
        int c = (kk * 4 + l4) ^ (row & 7);
        af[mi] = *(const bf16x8*)&As[row * 64 + c * 8];
      }
#pragma unroll
      for (int ni = 0; ni < 4; ni++) {
        int row = wc + ni * 16 + l15;
        int c = (kk * 4 + l4) ^ (row & 7);
        bfr[ni] = *(const bf16x8*)&Bs[row * 64 + c * 8];
      }
#pragma unroll
      for (int mi = 0; mi < 4; mi++)
#pragma unroll
        for (int ni = 0; ni < 4; ni++)
          acc[mi][ni] = __builtin_amdgcn_mfma_f32_16x16x32_bf16(af[mi], bfr[ni],
                                                                acc[mi][ni], 0, 0, 0);
    }
  }

#pragma unroll
  for (int mi = 0; mi < 4; mi++) {
    int rowb = m0 + wr + mi * 16 + l4 * 4;
#pragma unroll
    for (int ni = 0; ni < 4; ni++) {
      int col = n0 + wc + ni * 16 + l15;
#pragma unroll
      for (int r = 0; r < 4; r++)
        Cout[(size_t)(rowb + r) * Nn + col] = acc[mi][ni][r];
    }
  }
}

// ----------------------------------------------------------- attention ----
// (round-9/13 version — best measured: QBLK=128, 4 waves x 32 q-rows, KV
// tile 64 double-buffered K AND V staging, 2 blocks/CU. V staging is
// load-bearing: round-14's direct-global V read was 5.4x slower.)
__global__ __launch_bounds__(256, 2) void k_attn(
    const unsigned short* __restrict__ qb,
    const unsigned short* __restrict__ kb,
    const unsigned short* __restrict__ vt,
    unsigned short* __restrict__ ao) {
  __shared__ unsigned short Ks[2][64 * 128];  // [kv][d], 16B-chunk XOR swizzled
  __shared__ unsigned short Vs[2][64 * 128];  // [d][kv], swizzled
  __shared__ unsigned short Ps[4][32 * 64];   // per-wave P scratch, swizzled
  const int t = threadIdx.x;
  const int lane = t & 63, wid = t >> 6;
  const int l15 = lane & 15, l4 = lane >> 4;
  const int qt0 = blockIdx.x * 128;
  const int bh = blockIdx.y;
  const unsigned short* qbase = qb + (size_t)bh * 2048 * 128;
  const unsigned short* kbase = kb + (size_t)bh * 2048 * 128;
  const unsigned short* vbase = vt + (size_t)bh * 128 * 2048;

  bf16x8 qf[2][4];
#pragma unroll
  for (int mi = 0; mi < 2; mi++) {
    int qrow = qt0 + wid * 32 + mi * 16 + l15;
#pragma unroll
    for (int dk = 0; dk < 4; dk++)
      qf[mi][dk] = *(const bf16x8*)&qbase[(size_t)qrow * 128 + dk * 32 + l4 * 8];
  }

  f32x4 O[2][8];
#pragma unroll
  for (int mi = 0; mi < 2; mi++)
#pragma unroll
    for (int df = 0; df < 8; df++) O[mi][df] = (f32x4)0.f;
  float lsum[2][4];
#pragma unroll
  for (int mi = 0; mi < 2; mi++)
#pragma unroll
    for (int r = 0; r < 4; r++) lsum[mi][r] = 0.f;

  const float scale = 0.08838834764831845f;  // 1/sqrt(128)

  auto STAGE = [&](int kv0, int buf) {
#pragma unroll
    for (int j = 0; j < 4; j++) {
      int slotbase = j * 256 + wid * 64;
      int slot = slotbase + lane;
      int rowk = slot >> 4, ck = slot & 15;
      gload_lds16(&kbase[(size_t)(kv0 + rowk) * 128 + (ck ^ (rowk & 7)) * 8],
                  &Ks[buf][slotbase * 8]);
      int rowv = slot >> 3, cv = slot & 7;
      gload_lds16(&vbase[(size_t)rowv * 2048 + kv0 + (cv ^ (rowv & 7)) * 8],
                  &Vs[buf][slotbase * 8]);
    }
  };

  STAGE(0, 0);
  __syncthreads();

  for (int ti = 0; ti < 32; ti++) {
    const int cur = ti & 1;
    if (ti < 31) STAGE((ti + 1) * 64, cur ^ 1);  // prefetch next tile

    f32x4 s[2][4];
#pragma unroll
    for (int mi = 0; mi < 2; mi++)
#pragma unroll
      for (int ni = 0; ni < 4; ni++) s[mi][ni] = (f32x4)0.f;
#pragma unroll
    for (int dk = 0; dk < 4; dk++) {
      bf16x8 kf[4];
#pragma unroll
      for (int ni = 0; ni < 4; ni++) {
        int row = ni * 16 + l15;
        int c = (dk * 4 + l4) ^ (row & 7);
        kf[ni] = *(const bf16x8*)&Ks[cur][row * 128 + c * 8];
      }
#pragma unroll
      for (int mi = 0; mi < 2; mi++)
#pragma unroll
        for (int ni = 0; ni < 4; ni++)
          s[mi][ni] = __builtin_amdgcn_mfma_f32_16x16x32_bf16(qf[mi][dk], kf[ni],
                                                              s[mi][ni], 0, 0, 0);
    }

    unsigned short* pbase = &Ps[wid][0];
#pragma unroll
    for (int mi = 0; mi < 2; mi++)
#pragma unroll
      for (int ni = 0; ni < 4; ni++) {
        int col = ni * 16 + l15;
#pragma unroll
        for (int r = 0; r < 4; r++) {
          float p = __expf(s[mi][ni][r] * scale);
          lsum[mi][r] += p;
          int rowp = mi * 16 + l4 * 4 + r;
          pbase[rowp * 64 + (((col >> 3) ^ (rowp & 7)) << 3) + (col & 7)] = f2bf(p);
        }
      }

    bf16x8 pf[2][2];
#pragma unroll
    for (int mi = 0; mi < 2; mi++)
#pragma unroll
      for (int kk = 0; kk < 2; kk++) {
        int row = mi * 16 + l15;
        int c = (kk * 4 + l4) ^ (row & 7);
        pf[mi][kk] = *(const bf16x8*)&pbase[row * 64 + c * 8];
      }

#pragma unroll
    for (int df = 0; df < 8; df++) {
      bf16x8 vf[2];
#pragma unroll
      for (int kk = 0; kk < 2; kk++) {
        int row = df * 16 + l15;
        int c = (kk * 4 + l4) ^ (row & 7);
        vf[kk] = *(const bf16x8*)&Vs[cur][row * 64 + c * 8];
      }
#pragma unroll
      for (int mi = 0; mi < 2; mi++)
#pragma unroll
        for (int kk = 0; kk < 2; kk++)
          O[mi][df] = __builtin_amdgcn_mfma_f32_16x16x32_bf16(pf[mi][kk], vf[kk],
                                                              O[mi][df], 0, 0, 0);
    }

    __syncthreads();  // drains prefetch (vmcnt) + guards buffer reuse
  }

  float inv[2][4];
#pragma unroll
  for (int mi = 0; mi < 2; mi++)
#pragma unroll
    for (int r = 0; r < 4; r++) {
      float v = lsum[mi][r];
      v += __shfl_xor(v, 1, 64);
      v += __shfl_xor(v, 2, 64);
      v += __shfl_xor(v, 4, 64);
      v += __shfl_xor(v, 8, 64);
      inv[mi][r] = 1.0f / v;
    }

  const int b = bh >> 4, h = bh & 15;
#pragma unroll
  for (int mi = 0; mi < 2; mi++)
#pragma unroll
    for (int df = 0; df < 8; df++)
#pragma unroll
      for (int r = 0; r < 4; r++) {
        int tok = qt0 + wid * 32 + mi * 16 + l4 * 4 + r;
        ao[((size_t)(b * 2048 + tok)) * 2048 + h * 128 + df * 16 + l15] =
            f2bf(O[mi][df][r] * inv[mi][r]);
      }
}

// -------------------------------------------------------------- launch ----
extern "C" void kernel_launch(void* const* d_in, const int* in_sizes, int n_in,
                              void* d_out, int out_size, void* d_ws, size_t ws_size,
                              hipStream_t stream) {
  const float* x     = (const float*)d_in[0];  // [2,2048,2048]
  const float* freqs = (const float*)d_in[1];  // [2048,64,2]
  const float* wqkv  = (const float*)d_in[2];  // [2048,6144]
  const float* wo    = (const float*)d_in[3];  // [2048,2048]
  float* out = (float*)d_out;                  // [4096,2048]

  char* ws = (char*)d_ws;
  unsigned short* xb    = (unsigned short*)(ws + 0);          // 16.78 MB
  unsigned short* wqkvT = (unsigned short*)(ws + 16777216);   // 25.17 MB
  unsigned short* woT   = (unsigned short*)(ws + 41943040);   // 8.39 MB
  unsigned short* qb    = (unsigned short*)(ws + 50331648);   // 16.78 MB
  unsigned short* kb    = (unsigned short*)(ws + 67108864);   // 16.78 MB
  unsigned short* vt    = (unsigned short*)(ws + 83886080);   // 16.78 MB
  unsigned short* ao    = (unsigned short*)(ws + 100663296);  // 16.78 MB

  // fused prep: convert + both weight transposes in one launch
  k_prep<<<dim3(20480), dim3(256), 0, stream>>>(x, xb, wqkv, wqkvT, wo, woT);

  // qkv = xb @ wqkvT^T, fused RoPE, scatter (256x192 tiles, 2 clean rounds)
  k_gemm_qkv<<<dim3(512), dim3(512), 0, stream>>>(xb, wqkvT, qb, kb, vt, freqs);

  k_attn<<<dim3(16, 32), dim3(256), 0, stream>>>(qb, kb, vt, ao);

  // out = ao @ woT^T (naive 128^2, high occupancy — best measured)
  k_gemm_out<<<dim3(16, 32), dim3(256), 0, stream>>>(ao, woT, 2048, 2048, out);
}